// Round 7
// baseline (39.636 us; speedup 1.0000x reference)
//
#include <hip/hip_runtime.h>

#define FD 128          // feature dim
#define NB 1024         // batch
#define NC 16           // classes
#define NCB (NC * 16)   // 256 class blocks: 16 classes x (4x4 i,j chunks)
#define NFB 256         // fill blocks: 4 rows each
#define MAXM 112        // max supported class size (mean 64, sd ~7.7)
#define CKCAP 28        // ceil(MAXM/4) rows per chunk
#define LDP 132         // LDS row stride (floats): 16B-aligned, bank phase +4/row

// ONE kernel, no inter-block sync; output positions partitioned write-disjointly:
//   class blocks (bid < NCB): class c = bid>>4, (qi,qj) chunk pair -> scores.
//   fill blocks  (bid >= NCB): 4 rows each, zeros where labels differ.
// Member list built by deterministic ballot prefix-scan (identical in every
// block of a class) -> each (i,j) owned by exactly one block.
//
// R4 lesson: read W1 once per block (broadcast column loads), don't stream.
// R6 lesson: LDS pipe was NOT binding (3K cyc/SIMD < 8192-cyc FMA floor);
//   the binding constraint was 1 wave/SIMD absorbing all W1 L2 latency.
// Now: 1024-thread class blocks, thread = (half, rq, dg) owns 1 row x 8 dims
//   -> 16 waves/block = 4 waves/SIMD -> latency hidden by TLP; 8-reg acc.
__global__ __launch_bounds__(1024) void eg_one(
    const float* __restrict__ f, const int* __restrict__ labels,
    const float* __restrict__ W1, const float* __restrict__ b1,
    const float* __restrict__ w2, const float* __restrict__ b2,
    float* __restrict__ out)
{
  const int bid = blockIdx.x;
  const int tid = threadIdx.x;

  if (bid >= NCB) {
    // ---------- fill path: 4 rows per block ----------
    const int i = (bid - NCB) * 4 + (tid >> 8);
    const int li = labels[i];
    const int jb = tid & 255;
    float* __restrict__ row = out + (size_t)i * NB;
#pragma unroll
    for (int q = 0; q < 4; ++q) {
      const int j = jb + q * 256;
      if (labels[j] != li) row[j] = 0.f;   // masked elems must be exactly 0
    }
    return;
  }

  // ---------- class path ----------
  // lds union (barrier-separated lifetimes):
  //   phase 1: fs[2*CKCAP][LDP]  staged f rows (i-chunk then j-chunk)
  //   phase 2: his[CKCAP][LDP] | hjs[CKCAP][LDP]
  __shared__ __align__(16) float lds[2 * CKCAP * LDP];
  __shared__ int mem[MAXM];
  __shared__ int mcnt;
  float (*fs)[LDP]  = reinterpret_cast<float (*)[LDP]>(lds);
  float (*his)[LDP] = reinterpret_cast<float (*)[LDP]>(lds);
  float (*hjs)[LDP] = reinterpret_cast<float (*)[LDP]>(lds + CKCAP * LDP);

  const int c  = bid >> 4;
  const int qi = (bid >> 2) & 3;
  const int qj = bid & 3;

  // Deterministic member list (wave 0): ballot prefix over ascending j.
  if (tid < 64) {
    const int lane = tid;
    int base = 0;
    for (int w = 0; w < 16; ++w) {
      const int j = w * 64 + lane;
      const bool fl = (labels[j] == c);
      const unsigned long long msk = __ballot(fl);
      const int pos = base + __popcll(msk & ((1ull << lane) - 1ull));
      if (fl && pos < MAXM) mem[pos] = j;
      base += __popcll(msk);
    }
    if (lane == 0) mcnt = base < MAXM ? base : MAXM;
  }
  __syncthreads();

  const int m  = mcnt;
  const int ck = (m + 3) >> 2;                       // ceil(m/4) <= CKCAP
  const int i0 = qi * ck;
  const int SI = max(0, min(m, i0 + ck) - i0);
  const int j0 = qj * ck;
  const int SJ = max(0, min(m, j0 + ck) - j0);
  const int R  = SI + SJ;

  // Stage f rows of both chunks into LDS (coalesced float4).
  for (int idx = tid; idx < R * 32; idx += 1024) {
    const int r  = idx >> 5;
    const int fo = (idx & 31) << 2;
    const int g  = (r < SI) ? mem[i0 + r] : mem[j0 + (r - SI)];
    *reinterpret_cast<float4*>(&fs[r][fo]) =
        *reinterpret_cast<const float4*>(f + g * FD + fo);
  }
  __syncthreads();

  // h-compute: thread = (half, rq, dgi) -> 1 row x 8 dims in registers.
  // half 0 -> hi rows (b1 folded, W1[:D]); half 1 -> hj rows (W1[D:]).
  // Wave = 4 rq-groups x 16 dgi: W1 row-k float4 loads broadcast across the
  // 4 rq-groups (L1); fs[row][k] scalar reads: 4 distinct rows at bank phase
  // 4*rq -> disjoint banks, 16-lane broadcast each -> conflict-free.
  const int half = tid >> 9;
  const int rq   = (tid >> 4) & 31;
  const int dg   = (tid & 15) << 3;
  const int S     = half ? SJ : SI;
  const int rbase = half ? SI : 0;
  const bool valid = rq < S;
  const float* __restrict__ frow = fs[rbase + (valid ? rq : 0)];

  float acc[8];
  {
    float4 bA = make_float4(0.f, 0.f, 0.f, 0.f), bB = bA;
    if (!half) {
      bA = *reinterpret_cast<const float4*>(b1 + dg);
      bB = *reinterpret_cast<const float4*>(b1 + dg + 4);
    }
    acc[0] = bA.x; acc[1] = bA.y; acc[2] = bA.z; acc[3] = bA.w;
    acc[4] = bB.x; acc[5] = bB.y; acc[6] = bB.z; acc[7] = bB.w;
  }
  const float* __restrict__ Wp = W1 + half * FD * FD + dg;
#pragma unroll 4
  for (int k = 0; k < FD; ++k) {
    const float4 wA = *reinterpret_cast<const float4*>(Wp + k * FD);
    const float4 wB = *reinterpret_cast<const float4*>(Wp + k * FD + 4);
    const float fv = frow[k];
    acc[0] = fmaf(fv, wA.x, acc[0]); acc[1] = fmaf(fv, wA.y, acc[1]);
    acc[2] = fmaf(fv, wA.z, acc[2]); acc[3] = fmaf(fv, wA.w, acc[3]);
    acc[4] = fmaf(fv, wB.x, acc[4]); acc[5] = fmaf(fv, wB.y, acc[5]);
    acc[6] = fmaf(fv, wB.z, acc[6]); acc[7] = fmaf(fv, wB.w, acc[7]);
  }
  __syncthreads();   // all fs reads complete before lds is reused as his/hjs

  if (valid) {
    float* dst = (half ? hjs[rq] : his[rq]) + dg;
    *reinterpret_cast<float4*>(dst) =
        make_float4(acc[0], acc[1], acc[2], acc[3]);
    *reinterpret_cast<float4*>(dst + 4) =
        make_float4(acc[4], acc[5], acc[6], acc[7]);
  }
  __syncthreads();

  // pairs: per wave an 8x8 (i,j) tile; lane owns one pair; float4 d-loop.
  // 8 row-addresses spread across banks (phase 4/row), conflict-free.
  const int wv = tid >> 6, lane = tid & 63;
  const int a = lane >> 3, b = lane & 7;
  const int nti = (SI + 7) >> 3, ntj = (SJ + 7) >> 3;
  const float bb = b2[0];
  for (int t = wv; t < nti * ntj; t += 16) {
    const int ti = t / ntj, tj = t - ti * ntj;
    const int ii = ti * 8 + a, jj = tj * 8 + b;
    const int ic = ii < SI ? ii : SI - 1;   // clamp: keep LDS reads in-bounds
    const int jc = jj < SJ ? jj : SJ - 1;
    float acc2 = 0.f;
#pragma unroll 8
    for (int d = 0; d < FD; d += 4) {
      const float4 hv = *reinterpret_cast<const float4*>(&his[ic][d]);
      const float4 gv = *reinterpret_cast<const float4*>(&hjs[jc][d]);
      const float4 w4 = *reinterpret_cast<const float4*>(&w2[d]);
      acc2 = fmaf(fmaxf(hv.x + gv.x, 0.f), w4.x, acc2);
      acc2 = fmaf(fmaxf(hv.y + gv.y, 0.f), w4.y, acc2);
      acc2 = fmaf(fmaxf(hv.z + gv.z, 0.f), w4.z, acc2);
      acc2 = fmaf(fmaxf(hv.w + gv.w, 0.f), w4.w, acc2);
    }
    if (ii < SI && jj < SJ) {
      const int gi = mem[i0 + ii], gj = mem[j0 + jj];
      out[(size_t)gi * NB + gj] =
          (gi == gj) ? 0.f : 1.f / (1.f + __expf(-(acc2 + bb)));
    }
  }
}

extern "C" void kernel_launch(void* const* d_in, const int* in_sizes, int n_in,
                              void* d_out, int out_size, void* d_ws, size_t ws_size,
                              hipStream_t stream) {
  const float* f      = (const float*)d_in[0];
  const int*   labels = (const int*)d_in[1];
  const float* W1     = (const float*)d_in[2];
  const float* b1     = (const float*)d_in[3];
  const float* w2     = (const float*)d_in[4];
  const float* b2     = (const float*)d_in[5];
  float* out = (float*)d_out;

  eg_one<<<NCB + NFB, 1024, 0, stream>>>(f, labels, W1, b1, w2, b2, out);
}

// Round 8
// 23.343 us; speedup vs baseline: 1.6980x; 1.6980x over previous
//
#include <hip/hip_runtime.h>

#define FD 128          // feature dim
#define NB 1024         // batch
#define NC 16           // classes
#define NCB (NC * 16)   // 256 class blocks: 16 classes x (4x4 i,j chunks)
#define NFB 512         // fill blocks: 2 rows each
#define MAXM 112        // max supported class size (mean 64, sd ~7.7)
#define CKCAP 28        // ceil(MAXM/4) rows per chunk
#define LDP 132         // LDS row stride (floats): 16B-aligned, bank phase +4/row

// ONE kernel, no inter-block sync; output positions partitioned write-disjointly:
//   class blocks (bid < NCB): class c = bid>>4, (qi,qj) chunk pair -> scores.
//   fill blocks  (bid >= NCB): 2 rows each, zeros where labels differ.
// Member list built by deterministic ballot prefix-scan (identical in every
// block of a class) -> each (i,j) owned by exactly one block.
//
// R4: read W1 once per block-pass (broadcast column loads), don't stream.
// R6: 1 wave/SIMD can't hide the per-k W1 L2 stall (~128 x 270 cyc ~ 15 us).
// R7: 1 row/thread quadrupled W1 L1 requests (4 MB/CU ~ 26 us L1-BW floor).
// Now: 512-thr class blocks, thread = (half, rs, dg) = 4 contiguous rows x
//   4 dims (16 acc regs). W1: 1 dwordx4/thread/k, 512B unique/wave, 512 KB/CU.
//   2 waves/SIMD + k-lockstep (leader misses, followers L1-hit). Contiguous
//   row tiles -> typical S=16 skips half the waves entirely (r0 >= S).
__global__ __launch_bounds__(512) void eg_one(
    const float* __restrict__ f, const int* __restrict__ labels,
    const float* __restrict__ W1, const float* __restrict__ b1,
    const float* __restrict__ w2, const float* __restrict__ b2,
    float* __restrict__ out)
{
  const int bid = blockIdx.x;
  const int tid = threadIdx.x;

  if (bid >= NCB) {
    // ---------- fill path: 2 rows per block ----------
    const int i = (bid - NCB) * 2 + (tid >> 8);
    const int li = labels[i];
    const int jb = tid & 255;
    float* __restrict__ row = out + (size_t)i * NB;
#pragma unroll
    for (int q = 0; q < 4; ++q) {
      const int j = jb + q * 256;
      if (labels[j] != li) row[j] = 0.f;   // masked elems must be exactly 0
    }
    return;
  }

  // ---------- class path ----------
  // lds union (barrier-separated lifetimes):
  //   phase 1: fs[2*CKCAP][LDP]  staged f rows (i-chunk then j-chunk)
  //   phase 2: his[CKCAP][LDP] | hjs[CKCAP][LDP]
  __shared__ __align__(16) float lds[2 * CKCAP * LDP];
  __shared__ int mem[MAXM];
  __shared__ int mcnt;
  float (*fs)[LDP]  = reinterpret_cast<float (*)[LDP]>(lds);
  float (*his)[LDP] = reinterpret_cast<float (*)[LDP]>(lds);
  float (*hjs)[LDP] = reinterpret_cast<float (*)[LDP]>(lds + CKCAP * LDP);

  const int c  = bid >> 4;
  const int qi = (bid >> 2) & 3;
  const int qj = bid & 3;

  // Deterministic member list (wave 0): ballot prefix over ascending j.
  if (tid < 64) {
    const int lane = tid;
    int base = 0;
    for (int w = 0; w < 16; ++w) {
      const int j = w * 64 + lane;
      const bool fl = (labels[j] == c);
      const unsigned long long msk = __ballot(fl);
      const int pos = base + __popcll(msk & ((1ull << lane) - 1ull));
      if (fl && pos < MAXM) mem[pos] = j;
      base += __popcll(msk);
    }
    if (lane == 0) mcnt = base < MAXM ? base : MAXM;
  }
  __syncthreads();

  const int m  = mcnt;
  const int ck = (m + 3) >> 2;                       // ceil(m/4) <= CKCAP
  const int i0 = qi * ck;
  const int SI = max(0, min(m, i0 + ck) - i0);
  const int j0 = qj * ck;
  const int SJ = max(0, min(m, j0 + ck) - j0);
  const int R  = SI + SJ;

  // Stage f rows of both chunks into LDS (coalesced float4).
  for (int idx = tid; idx < R * 32; idx += 512) {
    const int r  = idx >> 5;
    const int fo = (idx & 31) << 2;
    const int g  = (r < SI) ? mem[i0 + r] : mem[j0 + (r - SI)];
    *reinterpret_cast<float4*>(&fs[r][fo]) =
        *reinterpret_cast<const float4*>(f + g * FD + fo);
  }
  __syncthreads();

  // h-compute: thread = (half, rs, dg) -> rows r0..r0+3 x dims dg*4..dg*4+3.
  // half 0 -> hi (b1 folded, W1[:D]); half 1 -> hj (W1[D:]).
  // Wave = 2 rs-groups x 32 dg: W1 row-k dwordx4 = 512B unique/wave;
  // fs b128 reads: 8 distinct rows/wave, bank phase 4/row -> conflict-free.
  const int half = tid >> 8;
  const int rs   = (tid >> 5) & 7;
  const int dg   = (tid & 31) << 2;
  const int S     = half ? SJ : SI;
  const int rbase = half ? SI : 0;
  const int r0    = rs * 4;

  float acc[4][4];
  if (r0 < S) {   // typical S=16: waves with rs>=4 skip the k-loop entirely
    float4 bA = make_float4(0.f, 0.f, 0.f, 0.f);
    if (!half) bA = *reinterpret_cast<const float4*>(b1 + dg);
#pragma unroll
    for (int rr = 0; rr < 4; ++rr) {
      acc[rr][0] = bA.x; acc[rr][1] = bA.y;
      acc[rr][2] = bA.z; acc[rr][3] = bA.w;
    }
    const float* frow[4];
#pragma unroll
    for (int rr = 0; rr < 4; ++rr) {
      const int r = r0 + rr;
      frow[rr] = fs[rbase + (r < S ? r : 0)];   // clamped rows never written
    }
    const float* __restrict__ Wp = W1 + half * FD * FD + dg;
#pragma unroll 2
    for (int k4 = 0; k4 < FD / 4; ++k4) {
      const int k = k4 << 2;
      float4 fq[4];
#pragma unroll
      for (int rr = 0; rr < 4; ++rr)
        fq[rr] = *reinterpret_cast<const float4*>(frow[rr] + k);
      const float* fqs = reinterpret_cast<const float*>(fq);  // static idx
#pragma unroll
      for (int kk = 0; kk < 4; ++kk) {
        const float4 w = *reinterpret_cast<const float4*>(Wp + (k + kk) * FD);
#pragma unroll
        for (int rr = 0; rr < 4; ++rr) {
          const float fv = fqs[rr * 4 + kk];
          acc[rr][0] = fmaf(fv, w.x, acc[rr][0]);
          acc[rr][1] = fmaf(fv, w.y, acc[rr][1]);
          acc[rr][2] = fmaf(fv, w.z, acc[rr][2]);
          acc[rr][3] = fmaf(fv, w.w, acc[rr][3]);
        }
      }
    }
  }
  __syncthreads();   // all fs reads complete before lds is reused as his/hjs

#pragma unroll
  for (int rr = 0; rr < 4; ++rr) {
    const int r = r0 + rr;
    if (r < S) {     // implies r0 < S -> acc initialized
      float* dst = (half ? hjs[r] : his[r]) + dg;
      *reinterpret_cast<float4*>(dst) =
          make_float4(acc[rr][0], acc[rr][1], acc[rr][2], acc[rr][3]);
    }
  }
  __syncthreads();

  // pairs: per wave an 8x8 (i,j) tile; lane owns one pair; float4 d-loop.
  // 8 row-addresses spread across banks (phase 4/row), conflict-free.
  const int wv = tid >> 6, lane = tid & 63;
  const int a = lane >> 3, b = lane & 7;
  const int nti = (SI + 7) >> 3, ntj = (SJ + 7) >> 3;
  const float bb = b2[0];
  for (int t = wv; t < nti * ntj; t += 8) {
    const int ti = t / ntj, tj = t - ti * ntj;
    const int ii = ti * 8 + a, jj = tj * 8 + b;
    const int ic = ii < SI ? ii : SI - 1;   // clamp: keep LDS reads in-bounds
    const int jc = jj < SJ ? jj : SJ - 1;
    float acc2 = 0.f;
#pragma unroll 8
    for (int d = 0; d < FD; d += 4) {
      const float4 hv = *reinterpret_cast<const float4*>(&his[ic][d]);
      const float4 gv = *reinterpret_cast<const float4*>(&hjs[jc][d]);
      const float4 w4 = *reinterpret_cast<const float4*>(&w2[d]);
      acc2 = fmaf(fmaxf(hv.x + gv.x, 0.f), w4.x, acc2);
      acc2 = fmaf(fmaxf(hv.y + gv.y, 0.f), w4.y, acc2);
      acc2 = fmaf(fmaxf(hv.z + gv.z, 0.f), w4.z, acc2);
      acc2 = fmaf(fmaxf(hv.w + gv.w, 0.f), w4.w, acc2);
    }
    if (ii < SI && jj < SJ) {
      const int gi = mem[i0 + ii], gj = mem[j0 + jj];
      out[(size_t)gi * NB + gj] =
          (gi == gj) ? 0.f : 1.f / (1.f + __expf(-(acc2 + bb)));
    }
  }
}

extern "C" void kernel_launch(void* const* d_in, const int* in_sizes, int n_in,
                              void* d_out, int out_size, void* d_ws, size_t ws_size,
                              hipStream_t stream) {
  const float* f      = (const float*)d_in[0];
  const int*   labels = (const int*)d_in[1];
  const float* W1     = (const float*)d_in[2];
  const float* b1     = (const float*)d_in[3];
  const float* w2     = (const float*)d_in[4];
  const float* b2     = (const float*)d_in[5];
  float* out = (float*)d_out;

  eg_one<<<NCB + NFB, 512, 0, stream>>>(f, labels, W1, b1, w2, b2, out);
}